// Round 3
// baseline (5266.349 us; speedup 1.0000x reference)
//
#include <hip/hip_runtime.h>
#include <math.h>

typedef unsigned int u32;

#define SPC   7488        // 24*24*13 crop spatial size
#define LOCS  451584      // 96*96*49
#define NX    56623104    // 2*32*96^3
#define PER_BC 884736     // 96^3

__device__ __forceinline__ u32 ford(float f){ u32 u=__float_as_uint(f); return (u&0x80000000u)? ~u : (u|0x80000000u); }
__device__ __forceinline__ float unford(u32 u){ return __uint_as_float((u&0x80000000u)?(u&0x7fffffffu):~u); }

#define TWO_PI 6.283185307179586476925f

// ---------------- init stats ----------------
__global__ void k_init(u32* mm, float* fstats){
  int t=threadIdx.x;
  if(t==0){ mm[0]=0u; mm[2]=0u; mm[1]=0xFFFFFFFFu; mm[3]=0xFFFFFFFFu; }
  if(t<128) fstats[t]=0.f;
}

// ---------------- K1: rfft along W (real 96 -> 49 complex), 4 lines/block, CT 96=8x12 ----------------
__global__ __launch_bounds__(384) void k_rfft_w(const float* __restrict__ x, float2* __restrict__ out){
  __shared__ float xs[96][4];
  __shared__ float2 Bs[96][4];
  __shared__ float twc[96], tws[96];
  int t=threadIdx.x;
  if(t<96){ float s,c; __sincosf((TWO_PI/96.f)*t,&s,&c); twc[t]=c; tws[t]=s; }
  long base=(long)blockIdx.x*384;
  { int l=t/96, w=t-l*96; xs[w][l]=x[base+l*96+w]; }
  __syncthreads();
  int col=t&3, u=t>>2;          // u in [0,96)
  int k1=u&7, n2=u>>3;          // n2 in [0,12)
  float ar=0.f, ai=0.f;
  #pragma unroll
  for(int n1=0;n1<8;n1++){
    float xv=xs[12*n1+n2][col];
    int m=(12*n1*k1)%96;        // W8^{n1 k1}
    ar += xv*twc[m];
    ai -= xv*tws[m];
  }
  { int m=(n2*k1)%96; float c=twc[m], s=tws[m];     // * W96^{n2 k1}
    Bs[k1*12+n2][col]=make_float2(ar*c+ai*s, ai*c-ar*s); }
  __syncthreads();
  if(u<49){
    int k2=u>>3, kk1=u&7;
    float xr=0.f, xi=0.f;
    #pragma unroll
    for(int j=0;j<12;j++){
      float2 b=Bs[kk1*12+j][col];
      int m=(8*j*k2)%96;        // W12^{j k2}
      float c=twc[m], s=tws[m];
      xr += b.x*c + b.y*s;
      xi += b.y*c - b.x*s;
    }
    out[((long)blockIdx.x*4+col)*49+u]=make_float2(xr,xi);
  }
}

// ---------------- K2/K3: complex FFT-96 along a middle axis; 7 columns/block; IN-PLACE safe ----------------
__global__ __launch_bounds__(672) void k_fft96(const float2* __restrict__ in, float2* __restrict__ out, int inner, int chunks){
  __shared__ float2 tile[672];
  __shared__ float2 Bs[672];
  __shared__ float twc[96], tws[96];
  int t=threadIdx.x;
  if(t<96){ float s,c; __sincosf((TWO_PI/96.f)*t,&s,&c); twc[t]=c; tws[t]=s; }
  int o=blockIdx.x/chunks, ch=blockIdx.x-o*chunks;
  long base=(long)o*96*inner + ch*7;
  { int row=t/7, ci=t-row*7;
    tile[t]=in[base+(long)row*inner+ci]; }
  __syncthreads();
  int col=t%7, u=t/7;           // u in [0,96)
  int k1=u&7, n2=u>>3;
  float ar=0.f, ai=0.f;
  #pragma unroll
  for(int n1=0;n1<8;n1++){
    float2 xv=tile[(12*n1+n2)*7+col];
    int m=(12*n1*k1)%96; float c=twc[m], s=tws[m];
    ar += xv.x*c + xv.y*s;
    ai += xv.y*c - xv.x*s;
  }
  { int m=(n2*k1)%96; float c=twc[m], s=tws[m];
    Bs[(k1*12+n2)*7+col]=make_float2(ar*c+ai*s, ai*c-ar*s); }
  __syncthreads();
  { int k2=u>>3, kk1=u&7;
    float xr=0.f, xi=0.f;
    #pragma unroll
    for(int j=0;j<12;j++){
      float2 b=Bs[(kk1*12+j)*7+col];
      int m=(8*j*k2)%96; float c=twc[m], s=tws[m];
      xr += b.x*c + b.y*s;
      xi += b.y*c - b.x*s;
    }
    out[base+(long)u*inner+col]=make_float2(xr,xi);
  }
}

// ---------------- K4: DFT-32 over C + butterfly over B, fused minmax + crop extract ----------------
__global__ __launch_bounds__(256) void k_fft_cb(const float2* __restrict__ F, float2* __restrict__ Fc, u32* __restrict__ mm){
  __shared__ float twc[32], tws[32];
  int t=threadIdx.x;
  if(t<32){ float s,c; __sincosf((TWO_PI/32.f)*t,&s,&c); twc[t]=c; tws[t]=s; }
  __syncthreads();
  int loc=blockIdx.x*256+t;     // exactly covers 451584
  float2 a0[32], a1[32];
  #pragma unroll
  for(int i=0;i<32;i++){ a0[i]=make_float2(0.f,0.f); a1[i]=make_float2(0.f,0.f); }
  for(int c=0;c<32;c++){
    float2 x0=F[(long)c*LOCS+loc];
    float2 x1=F[(long)(c+32)*LOCS+loc];
    float sr=x0.x+x1.x, si=x0.y+x1.y;
    float dr=x0.x-x1.x, di=x0.y-x1.y;
    #pragma unroll
    for(int kc=0;kc<32;kc++){
      int m=(c*kc)&31; float cc=twc[m], ss=tws[m];
      a0[kc].x += sr*cc+si*ss;
      a0[kc].y += si*cc-sr*ss;
      a1[kc].x += dr*cc+di*ss;
      a1[kc].y += di*cc-dr*ss;
    }
  }
  float rmx=-3.4e38f, rmn=3.4e38f, imx=-3.4e38f, imn=3.4e38f;
  #pragma unroll
  for(int i=0;i<32;i++){
    rmx=fmaxf(rmx,fmaxf(a0[i].x,a1[i].x)); rmn=fminf(rmn,fminf(a0[i].x,a1[i].x));
    imx=fmaxf(imx,fmaxf(a0[i].y,a1[i].y)); imn=fminf(imn,fminf(a0[i].y,a1[i].y));
  }
  #pragma unroll
  for(int off=32;off;off>>=1){
    rmx=fmaxf(rmx,__shfl_xor(rmx,off));
    rmn=fminf(rmn,__shfl_xor(rmn,off));
    imx=fmaxf(imx,__shfl_xor(imx,off));
    imn=fminf(imn,__shfl_xor(imn,off));
  }
  if((t&63)==0){
    atomicMax(&mm[0],ford(rmx)); atomicMin(&mm[1],ford(rmn));
    atomicMax(&mm[2],ford(imx)); atomicMin(&mm[3],ford(imn));
  }
  int d=loc/4704; int rem=loc-d*4704; int h=rem/49; int w=rem-h*49;
  bool in_d=(d<12)||(d>=84), in_h=(h<12)||(h>=84), in_w=(w<7)||(w>=43);
  if(in_d&&in_h&&in_w){
    int dd=(d<12)?d+12:d-84;
    int hh=(h<12)?h+12:h-84;
    int ww=(w<7)?w+6:w-43;
    int sp=(dd*24+hh)*13+ww;
    #pragma unroll
    for(int kc=0;kc<32;kc++){
      Fc[kc*SPC+sp]=a0[kc];
      Fc[(32+kc)*SPC+sp]=a1[kc];
    }
  }
}

// ---------------- C1: build normalized y [2][64][7488] ----------------
__global__ void k_build_y(const float2* __restrict__ Fc, const u32* __restrict__ mm, float* __restrict__ y){
  int idx=blockIdx.x*256+threadIdx.x;
  if(idx>=2*64*SPC) return;
  int s=idx%SPC; int bi=idx/SPC; int i=bi&63; int b=bi>>6;
  float rmax=unford(mm[0]), rmin=unford(mm[1]), imax=unford(mm[2]), imin=unford(mm[3]);
  int b2=(b+1)&1, c2=((i&31)+16)&31;
  float2 v=Fc[(b2*32+c2)*SPC+s];
  float val, lo, inv;
  if(i<32){ val=v.x; lo=rmin; inv=1.f/(rmax-rmin); }
  else    { val=v.y; lo=imin; inv=1.f/(imax-imin); }
  y[idx]=(val-lo)*inv;
}

// ---------------- C3: per (b,i) instance-norm stats of y ----------------
__global__ __launch_bounds__(256) void k_ystats(const float* __restrict__ y, float* __restrict__ ystats){
  __shared__ float red[8];
  int bi=blockIdx.x; int t=threadIdx.x;
  float s1=0.f,s2=0.f;
  for(int s=t;s<SPC;s+=256){ float v=y[(long)bi*SPC+s]; s1+=v; s2+=v*v; }
  #pragma unroll
  for(int off=32;off;off>>=1){ s1+=__shfl_down(s1,off); s2+=__shfl_down(s2,off); }
  if((t&63)==0){ red[(t>>6)*2]=s1; red[(t>>6)*2+1]=s2; }
  __syncthreads();
  if(t==0){
    float a=0.f,bq=0.f;
    for(int i2=0;i2<4;i2++){ a+=red[i2*2]; bq+=red[i2*2+1]; }
    float mean=a/(float)SPC; float var=bq/(float)SPC-mean*mean;
    ystats[bi*2]=mean; ystats[bi*2+1]=rsqrtf(var+1e-5f);
  }
}

// ---------------- C2: gate 1x1 conv (64->32) + its instance-norm stats ----------------
__global__ __launch_bounds__(256) void k_gate(const float* __restrict__ y, const float* __restrict__ gw, const float* __restrict__ gb,
                                              float* __restrict__ g, float* __restrict__ gstats){
  __shared__ float red[8];
  int bo=blockIdx.x; int t=threadIdx.x;
  int b=bo>>5, o=bo&31;
  float s1=0.f,s2=0.f;
  for(int s=t;s<SPC;s+=256){
    float acc=gb[o];
    #pragma unroll 8
    for(int i=0;i<64;i++) acc += gw[o*64+i]*y[((long)(b*64+i))*SPC+s];
    g[(long)bo*SPC+s]=acc; s1+=acc; s2+=acc*acc;
  }
  #pragma unroll
  for(int off=32;off;off>>=1){ s1+=__shfl_down(s1,off); s2+=__shfl_down(s2,off); }
  if((t&63)==0){ red[(t>>6)*2]=s1; red[(t>>6)*2+1]=s2; }
  __syncthreads();
  if(t==0){
    float a=0.f,bq=0.f;
    for(int i2=0;i2<4;i2++){ a+=red[i2*2]; bq+=red[i2*2+1]; }
    float mean=a/(float)SPC; float var=bq/(float)SPC-mean*mean;
    gstats[bo*2]=mean; gstats[bo*2+1]=rsqrtf(var+1e-5f);
  }
}

// ---------------- C4: compose processed complex spectrum G (ifftshift b/c maps folded in) ----------------
__global__ void k_compose(const float* __restrict__ y, const float* __restrict__ g,
                          const float* __restrict__ ystats, const float* __restrict__ gstats,
                          const float* __restrict__ ewW, const float* __restrict__ ewB,
                          const float* __restrict__ fw, const float* __restrict__ fb,
                          const u32* __restrict__ mm, float2* __restrict__ G){
  int idx=blockIdx.x*256+threadIdx.x;
  if(idx>=2*32*SPC) return;
  int s=idx%SPC; int bc=idx/SPC; int c2=bc&31; int b2=bc>>5;
  float rmax=unford(mm[0]), rmin=unford(mm[1]), imax=unford(mm[2]), imin=unford(mm[3]);
  int ir=b2*64+c2, ii=ir+32;
  float ynr=(y[(long)ir*SPC+s]-ystats[ir*2])*ystats[ir*2+1];
  float yni=(y[(long)ii*SPC+s]-ystats[ii*2])*ystats[ii*2+1];
  float y3r=(ynr*ewW[c2*SPC+s]+ewB[c2*SPC+s])*fw[c2]+fb[c2];
  float y3i=(yni*ewW[(c2+32)*SPC+s]+ewB[(c2+32)*SPC+s])*fw[c2+32]+fb[c2+32];
  int go=b2*32+c2;
  float gn=(g[(long)go*SPC+s]-gstats[go*2])*gstats[go*2+1];
  float filt=1.f/(1.f+expf(-gn));
  float outr=(y3r*(rmax-rmin)+rmin)*filt;
  float outi=(y3i*(imax-imin)+imin)*filt;
  G[(((b2+1)&1)*32+((c2+16)&31))*SPC+s]=make_float2(outr,outi);
}

// ---------------- I1: sparse inverse DFT along D: 24 coeffs -> 96, per (bc,hh) ----------------
__global__ __launch_bounds__(624) void k_inv_d(const float2* __restrict__ G, float2* __restrict__ o1){
  __shared__ float2 tile[312];
  __shared__ float twc[96], tws[96];
  int t=threadIdx.x;
  if(t<96){ float s,c; __sincosf((TWO_PI/96.f)*t,&s,&c); twc[t]=c; tws[t]=s; }
  int bc=blockIdx.x/24, hh=blockIdx.x%24;
  if(t<312){ int dd=t/13, ww=t-dd*13; tile[t]=G[((bc*24+dd)*24+hh)*13+ww]; }
  __syncthreads();
  int col=t%13, u=t/13;   // u in [0,48)
  float a1r=0.f,a1i=0.f,a2r=0.f,a2i=0.f;
  #pragma unroll
  for(int dd=0;dd<24;dd++){
    float2 v=tile[dd*13+col];
    int m=((dd+84)*u)%96;      // exp(+2*pi*i (dd-12) u /96)
    float c=twc[m], s=tws[m];
    float tr=v.x*c-v.y*s, ti=v.y*c+v.x*s;
    a1r+=tr; a1i+=ti;
    if(dd&1){ a2r-=tr; a2i-=ti; } else { a2r+=tr; a2i+=ti; }   // (-1)^(dd-12) for d=u+48
  }
  o1[((bc*96+u)*24+hh)*13+col]   =make_float2(a1r,a1i);
  o1[((bc*96+u+48)*24+hh)*13+col]=make_float2(a2r,a2i);
}

// ---------------- I2: sparse inverse DFT along H: 24 -> 96, per (bc,d) ----------------
__global__ __launch_bounds__(624) void k_inv_h(const float2* __restrict__ o1, float2* __restrict__ o2){
  __shared__ float2 tile[312];
  __shared__ float twc[96], tws[96];
  int t=threadIdx.x;
  if(t<96){ float s,c; __sincosf((TWO_PI/96.f)*t,&s,&c); twc[t]=c; tws[t]=s; }
  int bc=blockIdx.x/96, d=blockIdx.x%96;
  if(t<312){ tile[t]=o1[((long)(bc*96+d))*312+t]; }
  __syncthreads();
  int col=t%13, u=t/13;
  float a1r=0.f,a1i=0.f,a2r=0.f,a2i=0.f;
  #pragma unroll
  for(int hh=0;hh<24;hh++){
    float2 v=tile[hh*13+col];
    int m=((hh+84)*u)%96;
    float c=twc[m], s=tws[m];
    float tr=v.x*c-v.y*s, ti=v.y*c+v.x*s;
    a1r+=tr; a1i+=ti;
    if(hh&1){ a2r-=tr; a2i-=ti; } else { a2r+=tr; a2i+=ti; }
  }
  o2[((bc*96+d)*96+u)*13+col]   =make_float2(a1r,a1i);
  o2[((bc*96+d)*96+u+48)*13+col]=make_float2(a2r,a2i);
}

// ---------------- I3: 13-term irfft along W + spatial path + z(->d_out) + final-norm partial sums ----------------
__global__ __launch_bounds__(192) void k_inv_w(const float2* __restrict__ o2, const float* __restrict__ x,
                                               const float* __restrict__ sw, const float* __restrict__ sb,
                                               float* __restrict__ z, float* __restrict__ fstats){
  __shared__ float2 cf[2][13];
  __shared__ float twc[96], tws[96];
  __shared__ float red[8];
  int t=threadIdx.x;
  if(t<96){ float s,c; __sincosf((TWO_PI/96.f)*t,&s,&c); twc[t]=c; tws[t]=s; }
  long line0=(long)blockIdx.x*2;
  if(t<26){ int li=t/13, j=t-li*13; cf[li][j]=o2[(line0+li)*13+j]; }
  __syncthreads();
  int li=t/96, w=t-li*96;
  long line=line0+li;
  int bc=(int)(line/9216); int c=bc&31;
  // kw map: ww in {0..4} -> 43+ww ; ww==5 -> 48 (Nyquist, Re only) ; ww==6 -> 0 (DC, Re only) ; ww in {7..12} -> ww-6
  float rec = cf[li][6].x + ((w&1)? -cf[li][5].x : cf[li][5].x);
  #pragma unroll
  for(int ww=0;ww<13;ww++){
    if(ww==5||ww==6) continue;
    int kw=(ww<5)?(43+ww):(ww-6);
    int m=(kw*w)%96;
    rec += 2.f*(cf[li][ww].x*twc[m]-cf[li][ww].y*tws[m]);
  }
  float zv = x[line*96+w]*sw[c]+sb[c] + rec*(1.f/884736.f);
  z[line*96+w]=zv;
  float s1=zv, s2=zv*zv;
  #pragma unroll
  for(int off=32;off;off>>=1){ s1+=__shfl_down(s1,off); s2+=__shfl_down(s2,off); }
  if((t&63)==0){ red[(t>>6)*2]=s1; red[(t>>6)*2+1]=s2; }
  __syncthreads();
  if(t==0){
    float a=0.f,bq=0.f;
    for(int i2=0;i2<3;i2++){ a+=red[i2*2]; bq+=red[i2*2+1]; }
    atomicAdd(&fstats[bc*2],a); atomicAdd(&fstats[bc*2+1],bq);
  }
}

// ---------------- I4: final instance-norm + exact GELU (in-place on d_out) ----------------
__global__ void k_final(float* __restrict__ z, const float* __restrict__ fstats){
  long idx=(long)blockIdx.x*256+threadIdx.x;
  if(idx>=NX) return;
  int bc=(int)(idx/PER_BC);
  float mean=fstats[bc*2]*(1.f/884736.f);
  float var =fstats[bc*2+1]*(1.f/884736.f)-mean*mean;
  float zn=(z[idx]-mean)*rsqrtf(var+1e-5f);
  z[idx]=0.5f*zn*(1.f+erff(zn*0.7071067811865475f));
}

extern "C" void kernel_launch(void* const* d_in, const int* in_sizes, int n_in,
                              void* d_out, int out_size, void* d_ws, size_t ws_size,
                              hipStream_t stream){
  const float* x  =(const float*)d_in[0];
  const float* sw =(const float*)d_in[1];
  const float* sb =(const float*)d_in[2];
  const float* ewW=(const float*)d_in[3];
  const float* ewB=(const float*)d_in[4];
  const float* fw =(const float*)d_in[5];
  const float* fb =(const float*)d_in[6];
  const float* gw =(const float*)d_in[7];
  const float* gb =(const float*)d_in[8];
  float* ws=(float*)d_ws;

  // workspace layout (float offsets); total 61,157,892 floats = 244.6 MB
  if(ws_size < (size_t)61157892*4) return;   // guard: avoid OOB container crash
  float2* bufA=(float2*)(ws);                  // 28,901,376 float2 (231 MB), forward spectrum (in-place FFT passes)
  float2* o1  =(float2*)(ws);                  // overlay bufA (dead after k_fft_cb): 1,916,928 float2
  float2* o2  =(float2*)(ws+3833856);          // overlay bufA: 7,667,712 float2
  float2* Fc  =(float2*)(ws+57802752);         // 479,232 float2
  float*  y   = ws+58761216;                   // 958,464
  float*  g   = ws+59719680;                   // 479,232
  float2* G   =(float2*)(ws+60198912);         // 479,232 float2
  u32*    mm  =(u32*)(ws+61157376);            // 4
  float*  ystats=ws+61157380;                  // 256
  float*  gstats=ws+61157636;                  // 128
  float*  fstats=ws+61157764;                  // 128
  float*  z   =(float*)d_out;                  // z lives in d_out; k_final is in-place elementwise

  k_init   <<<dim3(1),     dim3(256),0,stream>>>(mm,fstats);
  k_rfft_w <<<dim3(147456),dim3(384),0,stream>>>(x,bufA);
  k_fft96  <<<dim3(43008), dim3(672),0,stream>>>(bufA,bufA,49,7);     // H axis, in-place
  k_fft96  <<<dim3(43008), dim3(672),0,stream>>>(bufA,bufA,4704,672); // D axis, in-place
  k_fft_cb <<<dim3(1764),  dim3(256),0,stream>>>(bufA,Fc,mm);
  k_build_y<<<dim3(3744),  dim3(256),0,stream>>>(Fc,mm,y);
  k_ystats <<<dim3(128),   dim3(256),0,stream>>>(y,ystats);
  k_gate   <<<dim3(64),    dim3(256),0,stream>>>(y,gw,gb,g,gstats);
  k_compose<<<dim3(1872),  dim3(256),0,stream>>>(y,g,ystats,gstats,ewW,ewB,fw,fb,mm,G);
  k_inv_d  <<<dim3(1536),  dim3(624),0,stream>>>(G,o1);
  k_inv_h  <<<dim3(6144),  dim3(624),0,stream>>>(o1,o2);
  k_inv_w  <<<dim3(294912),dim3(192),0,stream>>>(o2,x,sw,sb,z,fstats);
  k_final  <<<dim3(221184),dim3(256),0,stream>>>(z,fstats);
}

// Round 4
// 2107.457 us; speedup vs baseline: 2.4989x; 2.4989x over previous
//
#include <hip/hip_runtime.h>
#include <math.h>

typedef unsigned int u32;

#define SPC   7488        // 24*24*13 crop spatial size
#define LOCS  451584      // 96*96*49
#define NX    56623104    // 2*32*96^3
#define PER_BC 884736     // 96^3

__device__ __forceinline__ u32 ford(float f){ u32 u=__float_as_uint(f); return (u&0x80000000u)? ~u : (u|0x80000000u); }
__device__ __forceinline__ float unford(u32 u){ return __uint_as_float((u&0x80000000u)?(u&0x7fffffffu):~u); }

#define TWO_PI 6.283185307179586476925f

// ---------------- init stats ----------------
__global__ void k_init(u32* mm, float* fstats){
  int t=threadIdx.x;
  if(t==0){ mm[0]=0u; mm[2]=0u; mm[1]=0xFFFFFFFFu; mm[3]=0xFFFFFFFFu; }
  if(t<128) fstats[t]=0.f;
}

// ---------------- K1: rfft along W (real 96 -> 49 complex), 4 lines/block, CT 96=8x12 ----------------
__global__ __launch_bounds__(384) void k_rfft_w(const float* __restrict__ x, float2* __restrict__ out){
  __shared__ float xs[96][4];
  __shared__ float2 Bs[96][4];
  __shared__ float twc[96], tws[96];
  int t=threadIdx.x;
  if(t<96){ float s,c; __sincosf((TWO_PI/96.f)*t,&s,&c); twc[t]=c; tws[t]=s; }
  long base=(long)blockIdx.x*384;
  { int l=t/96, w=t-l*96; xs[w][l]=x[base+l*96+w]; }
  __syncthreads();
  int col=t&3, u=t>>2;          // u in [0,96)
  int k1=u&7, n2=u>>3;          // n2 in [0,12)
  float ar=0.f, ai=0.f;
  #pragma unroll
  for(int n1=0;n1<8;n1++){
    float xv=xs[12*n1+n2][col];
    int m=(12*n1*k1)%96;        // W8^{n1 k1}
    ar += xv*twc[m];
    ai -= xv*tws[m];
  }
  { int m=(n2*k1)%96; float c=twc[m], s=tws[m];     // * W96^{n2 k1}
    Bs[k1*12+n2][col]=make_float2(ar*c+ai*s, ai*c-ar*s); }
  __syncthreads();
  if(u<49){
    int k2=u>>3, kk1=u&7;
    float xr=0.f, xi=0.f;
    #pragma unroll
    for(int j=0;j<12;j++){
      float2 b=Bs[kk1*12+j][col];
      int m=(8*j*k2)%96;        // W12^{j k2}
      float c=twc[m], s=tws[m];
      xr += b.x*c + b.y*s;
      xi += b.y*c - b.x*s;
    }
    out[((long)blockIdx.x*4+col)*49+u]=make_float2(xr,xi);
  }
}

// ---------------- K2/K3: complex FFT-96 along a middle axis; 7 columns/block; IN-PLACE safe ----------------
__global__ __launch_bounds__(672) void k_fft96(const float2* __restrict__ in, float2* __restrict__ out, int inner, int chunks){
  __shared__ float2 tile[672];
  __shared__ float2 Bs[672];
  __shared__ float twc[96], tws[96];
  int t=threadIdx.x;
  if(t<96){ float s,c; __sincosf((TWO_PI/96.f)*t,&s,&c); twc[t]=c; tws[t]=s; }
  int o=blockIdx.x/chunks, ch=blockIdx.x-o*chunks;
  long base=(long)o*96*inner + ch*7;
  { int row=t/7, ci=t-row*7;
    tile[t]=in[base+(long)row*inner+ci]; }
  __syncthreads();
  int col=t%7, u=t/7;           // u in [0,96)
  int k1=u&7, n2=u>>3;
  float ar=0.f, ai=0.f;
  #pragma unroll
  for(int n1=0;n1<8;n1++){
    float2 xv=tile[(12*n1+n2)*7+col];
    int m=(12*n1*k1)%96; float c=twc[m], s=tws[m];
    ar += xv.x*c + xv.y*s;
    ai += xv.y*c - xv.x*s;
  }
  { int m=(n2*k1)%96; float c=twc[m], s=tws[m];
    Bs[(k1*12+n2)*7+col]=make_float2(ar*c+ai*s, ai*c-ar*s); }
  __syncthreads();
  { int k2=u>>3, kk1=u&7;
    float xr=0.f, xi=0.f;
    #pragma unroll
    for(int j=0;j<12;j++){
      float2 b=Bs[(kk1*12+j)*7+col];
      int m=(8*j*k2)%96; float c=twc[m], s=tws[m];
      xr += b.x*c + b.y*s;
      xi += b.y*c - b.x*s;
    }
    out[base+(long)u*inner+col]=make_float2(xr,xi);
  }
}

// ---------------- K4: DFT-32 over C + butterfly over B, fused minmax + crop extract ----------------
__global__ __launch_bounds__(256) void k_fft_cb(const float2* __restrict__ F, float2* __restrict__ Fc, u32* __restrict__ mm){
  __shared__ float twc[32], tws[32];
  int t=threadIdx.x;
  if(t<32){ float s,c; __sincosf((TWO_PI/32.f)*t,&s,&c); twc[t]=c; tws[t]=s; }
  __syncthreads();
  int loc=blockIdx.x*256+t;     // exactly covers 451584
  float2 a0[32], a1[32];
  #pragma unroll
  for(int i=0;i<32;i++){ a0[i]=make_float2(0.f,0.f); a1[i]=make_float2(0.f,0.f); }
  for(int c=0;c<32;c++){
    float2 x0=F[(long)c*LOCS+loc];
    float2 x1=F[(long)(c+32)*LOCS+loc];
    float sr=x0.x+x1.x, si=x0.y+x1.y;
    float dr=x0.x-x1.x, di=x0.y-x1.y;
    #pragma unroll
    for(int kc=0;kc<32;kc++){
      int m=(c*kc)&31; float cc=twc[m], ss=tws[m];
      a0[kc].x += sr*cc+si*ss;
      a0[kc].y += si*cc-sr*ss;
      a1[kc].x += dr*cc+di*ss;
      a1[kc].y += di*cc-dr*ss;
    }
  }
  float rmx=-3.4e38f, rmn=3.4e38f, imx=-3.4e38f, imn=3.4e38f;
  #pragma unroll
  for(int i=0;i<32;i++){
    rmx=fmaxf(rmx,fmaxf(a0[i].x,a1[i].x)); rmn=fminf(rmn,fminf(a0[i].x,a1[i].x));
    imx=fmaxf(imx,fmaxf(a0[i].y,a1[i].y)); imn=fminf(imn,fminf(a0[i].y,a1[i].y));
  }
  #pragma unroll
  for(int off=32;off;off>>=1){
    rmx=fmaxf(rmx,__shfl_xor(rmx,off));
    rmn=fminf(rmn,__shfl_xor(rmn,off));
    imx=fmaxf(imx,__shfl_xor(imx,off));
    imn=fminf(imn,__shfl_xor(imn,off));
  }
  if((t&63)==0){
    atomicMax(&mm[0],ford(rmx)); atomicMin(&mm[1],ford(rmn));
    atomicMax(&mm[2],ford(imx)); atomicMin(&mm[3],ford(imn));
  }
  int d=loc/4704; int rem=loc-d*4704; int h=rem/49; int w=rem-h*49;
  bool in_d=(d<12)||(d>=84), in_h=(h<12)||(h>=84), in_w=(w<7)||(w>=43);
  if(in_d&&in_h&&in_w){
    int dd=(d<12)?d+12:d-84;
    int hh=(h<12)?h+12:h-84;
    int ww=(w<7)?w+6:w-43;
    int sp=(dd*24+hh)*13+ww;
    #pragma unroll
    for(int kc=0;kc<32;kc++){
      Fc[kc*SPC+sp]=a0[kc];
      Fc[(32+kc)*SPC+sp]=a1[kc];
    }
  }
}

// ---------------- C1: build normalized y [2][64][7488] ----------------
__global__ void k_build_y(const float2* __restrict__ Fc, const u32* __restrict__ mm, float* __restrict__ y){
  int idx=blockIdx.x*256+threadIdx.x;
  if(idx>=2*64*SPC) return;
  int s=idx%SPC; int bi=idx/SPC; int i=bi&63; int b=bi>>6;
  float rmax=unford(mm[0]), rmin=unford(mm[1]), imax=unford(mm[2]), imin=unford(mm[3]);
  int b2=(b+1)&1, c2=((i&31)+16)&31;
  float2 v=Fc[(b2*32+c2)*SPC+s];
  float val, lo, inv;
  if(i<32){ val=v.x; lo=rmin; inv=1.f/(rmax-rmin); }
  else    { val=v.y; lo=imin; inv=1.f/(imax-imin); }
  y[idx]=(val-lo)*inv;
}

// ---------------- C3: per (b,i) instance-norm stats of y ----------------
__global__ __launch_bounds__(256) void k_ystats(const float* __restrict__ y, float* __restrict__ ystats){
  __shared__ float red[8];
  int bi=blockIdx.x; int t=threadIdx.x;
  float s1=0.f,s2=0.f;
  for(int s=t;s<SPC;s+=256){ float v=y[(long)bi*SPC+s]; s1+=v; s2+=v*v; }
  #pragma unroll
  for(int off=32;off;off>>=1){ s1+=__shfl_down(s1,off); s2+=__shfl_down(s2,off); }
  if((t&63)==0){ red[(t>>6)*2]=s1; red[(t>>6)*2+1]=s2; }
  __syncthreads();
  if(t==0){
    float a=0.f,bq=0.f;
    for(int i2=0;i2<4;i2++){ a+=red[i2*2]; bq+=red[i2*2+1]; }
    float mean=a/(float)SPC; float var=bq/(float)SPC-mean*mean;
    ystats[bi*2]=mean; ystats[bi*2+1]=rsqrtf(var+1e-5f);
  }
}

// ---------------- C2: gate 1x1 conv (64->32) + its instance-norm stats ----------------
__global__ __launch_bounds__(256) void k_gate(const float* __restrict__ y, const float* __restrict__ gw, const float* __restrict__ gb,
                                              float* __restrict__ g, float* __restrict__ gstats){
  __shared__ float red[8];
  int bo=blockIdx.x; int t=threadIdx.x;
  int b=bo>>5, o=bo&31;
  float s1=0.f,s2=0.f;
  for(int s=t;s<SPC;s+=256){
    float acc=gb[o];
    #pragma unroll 8
    for(int i=0;i<64;i++) acc += gw[o*64+i]*y[((long)(b*64+i))*SPC+s];
    g[(long)bo*SPC+s]=acc; s1+=acc; s2+=acc*acc;
  }
  #pragma unroll
  for(int off=32;off;off>>=1){ s1+=__shfl_down(s1,off); s2+=__shfl_down(s2,off); }
  if((t&63)==0){ red[(t>>6)*2]=s1; red[(t>>6)*2+1]=s2; }
  __syncthreads();
  if(t==0){
    float a=0.f,bq=0.f;
    for(int i2=0;i2<4;i2++){ a+=red[i2*2]; bq+=red[i2*2+1]; }
    float mean=a/(float)SPC; float var=bq/(float)SPC-mean*mean;
    gstats[bo*2]=mean; gstats[bo*2+1]=rsqrtf(var+1e-5f);
  }
}

// ---------------- C4: compose processed complex spectrum G (ifftshift b/c maps folded in) ----------------
__global__ void k_compose(const float* __restrict__ y, const float* __restrict__ g,
                          const float* __restrict__ ystats, const float* __restrict__ gstats,
                          const float* __restrict__ ewW, const float* __restrict__ ewB,
                          const float* __restrict__ fw, const float* __restrict__ fb,
                          const u32* __restrict__ mm, float2* __restrict__ G){
  int idx=blockIdx.x*256+threadIdx.x;
  if(idx>=2*32*SPC) return;
  int s=idx%SPC; int bc=idx/SPC; int c2=bc&31; int b2=bc>>5;
  float rmax=unford(mm[0]), rmin=unford(mm[1]), imax=unford(mm[2]), imin=unford(mm[3]);
  int ir=b2*64+c2, ii=ir+32;
  float ynr=(y[(long)ir*SPC+s]-ystats[ir*2])*ystats[ir*2+1];
  float yni=(y[(long)ii*SPC+s]-ystats[ii*2])*ystats[ii*2+1];
  float y3r=(ynr*ewW[c2*SPC+s]+ewB[c2*SPC+s])*fw[c2]+fb[c2];
  float y3i=(yni*ewW[(c2+32)*SPC+s]+ewB[(c2+32)*SPC+s])*fw[c2+32]+fb[c2+32];
  int go=b2*32+c2;
  float gn=(g[(long)go*SPC+s]-gstats[go*2])*gstats[go*2+1];
  float filt=1.f/(1.f+expf(-gn));
  float outr=(y3r*(rmax-rmin)+rmin)*filt;
  float outi=(y3i*(imax-imin)+imin)*filt;
  G[(((b2+1)&1)*32+((c2+16)&31))*SPC+s]=make_float2(outr,outi);
}

// ---------------- I1: sparse inverse DFT along D: 24 coeffs -> 96, per (bc,hh) ----------------
__global__ __launch_bounds__(624) void k_inv_d(const float2* __restrict__ G, float2* __restrict__ o1){
  __shared__ float2 tile[312];
  __shared__ float twc[96], tws[96];
  int t=threadIdx.x;
  if(t<96){ float s,c; __sincosf((TWO_PI/96.f)*t,&s,&c); twc[t]=c; tws[t]=s; }
  int bc=blockIdx.x/24, hh=blockIdx.x%24;
  if(t<312){ int dd=t/13, ww=t-dd*13; tile[t]=G[((bc*24+dd)*24+hh)*13+ww]; }
  __syncthreads();
  int col=t%13, u=t/13;   // u in [0,48)
  float a1r=0.f,a1i=0.f,a2r=0.f,a2i=0.f;
  #pragma unroll
  for(int dd=0;dd<24;dd++){
    float2 v=tile[dd*13+col];
    int m=((dd+84)*u)%96;      // exp(+2*pi*i (dd-12) u /96)
    float c=twc[m], s=tws[m];
    float tr=v.x*c-v.y*s, ti=v.y*c+v.x*s;
    a1r+=tr; a1i+=ti;
    if(dd&1){ a2r-=tr; a2i-=ti; } else { a2r+=tr; a2i+=ti; }   // (-1)^(dd-12) for d=u+48
  }
  o1[((bc*96+u)*24+hh)*13+col]   =make_float2(a1r,a1i);
  o1[((bc*96+u+48)*24+hh)*13+col]=make_float2(a2r,a2i);
}

// ---------------- I2: sparse inverse DFT along H: 24 -> 96, per (bc,d) ----------------
__global__ __launch_bounds__(624) void k_inv_h(const float2* __restrict__ o1, float2* __restrict__ o2){
  __shared__ float2 tile[312];
  __shared__ float twc[96], tws[96];
  int t=threadIdx.x;
  if(t<96){ float s,c; __sincosf((TWO_PI/96.f)*t,&s,&c); twc[t]=c; tws[t]=s; }
  int bc=blockIdx.x/96, d=blockIdx.x%96;
  if(t<312){ tile[t]=o1[((long)(bc*96+d))*312+t]; }
  __syncthreads();
  int col=t%13, u=t/13;
  float a1r=0.f,a1i=0.f,a2r=0.f,a2i=0.f;
  #pragma unroll
  for(int hh=0;hh<24;hh++){
    float2 v=tile[hh*13+col];
    int m=((hh+84)*u)%96;
    float c=twc[m], s=tws[m];
    float tr=v.x*c-v.y*s, ti=v.y*c+v.x*s;
    a1r+=tr; a1i+=ti;
    if(hh&1){ a2r-=tr; a2i-=ti; } else { a2r+=tr; a2i+=ti; }
  }
  o2[((bc*96+d)*96+u)*13+col]   =make_float2(a1r,a1i);
  o2[((bc*96+d)*96+u+48)*13+col]=make_float2(a2r,a2i);
}

// ---------------- I3: 13-term irfft along W + spatial path + z(->d_out) + final-norm partial sums ----------------
// One block per (bc,d) plane: 96 h-lines x 96 w. 384 threads: li=t/96 handles h=li,li+4,...
// Per-thread w is FIXED -> 11 twiddle pairs live in registers; coeffs LDS-broadcast per line.
__global__ __launch_bounds__(384) void k_inv_w(const float2* __restrict__ o2, const float* __restrict__ x,
                                               const float* __restrict__ sw, const float* __restrict__ sb,
                                               float* __restrict__ z, float* __restrict__ fstats){
  __shared__ float2 cf[96*13];
  __shared__ float red[12];
  int t=threadIdx.x;
  int bc=blockIdx.x/96, d=blockIdx.x%96;
  const float2* src=o2+(long)(bc*96+d)*1248;
  for(int i=t;i<1248;i+=384) cf[i]=src[i];
  __syncthreads();
  int li=t/96, w=t-li*96;
  // kw map: ww in {0..4} -> 43+ww ; ww==5 -> 48 (Nyquist, Re only) ; ww==6 -> 0 (DC, Re only) ; ww in {7..12} -> ww-6
  float twr[13], twi[13];
  #pragma unroll
  for(int ww=0;ww<13;ww++){
    if(ww==5||ww==6){ twr[ww]=0.f; twi[ww]=0.f; continue; }
    int kw=(ww<5)?(43+ww):(ww-6);
    float s,c; __sincosf((TWO_PI/96.f)*(float)((kw*w)%96),&s,&c);
    twr[ww]=c; twi[ww]=s;
  }
  int c=bc&31;
  float swc=sw[c], sbc=sb[c];
  float par=(w&1)? -1.f:1.f;
  long base=(long)bc*PER_BC+(long)d*9216;
  float s1=0.f,s2=0.f;
  for(int h=li;h<96;h+=4){
    const float2* L=&cf[h*13];
    float rec = L[6].x + par*L[5].x;
    #pragma unroll
    for(int ww=0;ww<13;ww++){
      if(ww==5||ww==6) continue;
      rec += 2.f*(L[ww].x*twr[ww]-L[ww].y*twi[ww]);
    }
    float zv = x[base+h*96+w]*swc+sbc + rec*(1.f/884736.f);
    z[base+h*96+w]=zv;
    s1+=zv; s2+=zv*zv;
  }
  #pragma unroll
  for(int off=32;off;off>>=1){ s1+=__shfl_down(s1,off); s2+=__shfl_down(s2,off); }
  if((t&63)==0){ red[(t>>6)*2]=s1; red[(t>>6)*2+1]=s2; }
  __syncthreads();
  if(t==0){
    float a=0.f,bq=0.f;
    for(int i2=0;i2<6;i2++){ a+=red[i2*2]; bq+=red[i2*2+1]; }
    atomicAdd(&fstats[bc*2],a); atomicAdd(&fstats[bc*2+1],bq);
  }
}

// ---------------- I4: final instance-norm + exact GELU (in-place on d_out) ----------------
__global__ void k_final(float* __restrict__ z, const float* __restrict__ fstats){
  long idx=(long)blockIdx.x*256+threadIdx.x;
  if(idx>=NX) return;
  int bc=(int)(idx/PER_BC);
  float mean=fstats[bc*2]*(1.f/884736.f);
  float var =fstats[bc*2+1]*(1.f/884736.f)-mean*mean;
  float zn=(z[idx]-mean)*rsqrtf(var+1e-5f);
  z[idx]=0.5f*zn*(1.f+erff(zn*0.7071067811865475f));
}

extern "C" void kernel_launch(void* const* d_in, const int* in_sizes, int n_in,
                              void* d_out, int out_size, void* d_ws, size_t ws_size,
                              hipStream_t stream){
  const float* x  =(const float*)d_in[0];
  const float* sw =(const float*)d_in[1];
  const float* sb =(const float*)d_in[2];
  const float* ewW=(const float*)d_in[3];
  const float* ewB=(const float*)d_in[4];
  const float* fw =(const float*)d_in[5];
  const float* fb =(const float*)d_in[6];
  const float* gw =(const float*)d_in[7];
  const float* gb =(const float*)d_in[8];
  float* ws=(float*)d_ws;

  // workspace layout (float offsets); total 61,157,892 floats = 244.6 MB
  if(ws_size < (size_t)61157892*4) return;   // guard: avoid OOB container crash
  float2* bufA=(float2*)(ws);                  // 28,901,376 float2 (231 MB), forward spectrum (in-place FFT passes)
  float2* o1  =(float2*)(ws);                  // overlay bufA (dead after k_fft_cb): 1,916,928 float2
  float2* o2  =(float2*)(ws+3833856);          // overlay bufA: 7,667,712 float2
  float2* Fc  =(float2*)(ws+57802752);         // 479,232 float2
  float*  y   = ws+58761216;                   // 958,464
  float*  g   = ws+59719680;                   // 479,232
  float2* G   =(float2*)(ws+60198912);         // 479,232 float2
  u32*    mm  =(u32*)(ws+61157376);            // 4
  float*  ystats=ws+61157380;                  // 256
  float*  gstats=ws+61157636;                  // 128
  float*  fstats=ws+61157764;                  // 128
  float*  z   =(float*)d_out;                  // z lives in d_out; k_final is in-place elementwise

  k_init   <<<dim3(1),     dim3(256),0,stream>>>(mm,fstats);
  k_rfft_w <<<dim3(147456),dim3(384),0,stream>>>(x,bufA);
  k_fft96  <<<dim3(43008), dim3(672),0,stream>>>(bufA,bufA,49,7);     // H axis, in-place
  k_fft96  <<<dim3(43008), dim3(672),0,stream>>>(bufA,bufA,4704,672); // D axis, in-place
  k_fft_cb <<<dim3(1764),  dim3(256),0,stream>>>(bufA,Fc,mm);
  k_build_y<<<dim3(3744),  dim3(256),0,stream>>>(Fc,mm,y);
  k_ystats <<<dim3(128),   dim3(256),0,stream>>>(y,ystats);
  k_gate   <<<dim3(64),    dim3(256),0,stream>>>(y,gw,gb,g,gstats);
  k_compose<<<dim3(1872),  dim3(256),0,stream>>>(y,g,ystats,gstats,ewW,ewB,fw,fb,mm,G);
  k_inv_d  <<<dim3(1536),  dim3(624),0,stream>>>(G,o1);
  k_inv_h  <<<dim3(6144),  dim3(624),0,stream>>>(o1,o2);
  k_inv_w  <<<dim3(6144),  dim3(384),0,stream>>>(o2,x,sw,sb,z,fstats);
  k_final  <<<dim3(221184),dim3(256),0,stream>>>(z,fstats);
}